// Round 1
// baseline (98.367 us; speedup 1.0000x reference)
//
#include <hip/hip_runtime.h>
#include <hip/hip_bf16.h>

#define B_N   4096
#define DIM   512
#define NCLS  100
#define MARGIN 0.1f
#define ONE_EPS (1.0f - 1e-5f)

typedef __attribute__((ext_vector_type(8))) short short8;   // 8 bf16 = 4 VGPRs (MFMA A/B frag)
typedef __attribute__((ext_vector_type(4))) float f32x4;    // MFMA C/D frag
typedef unsigned short ushort_t;

__device__ __forceinline__ void async_load16(const void* g, void* l) {
    __builtin_amdgcn_global_load_lds(
        (const __attribute__((address_space(1))) unsigned int*)g,
        (__attribute__((address_space(3))) unsigned int*)l,
        16, 0, 0);
}

// ---------- block(256) reductions: result broadcast to all threads ----------
__device__ __forceinline__ float blk_sum(float v, float* red) {
#pragma unroll
    for (int m = 32; m; m >>= 1) v += __shfl_xor(v, m, 64);
    const int w = threadIdx.x >> 6;
    if ((threadIdx.x & 63) == 0) red[w] = v;
    __syncthreads();
    v = red[0] + red[1] + red[2] + red[3];
    __syncthreads();
    return v;
}
__device__ __forceinline__ float blk_min(float v, float* red) {
#pragma unroll
    for (int m = 32; m; m >>= 1) v = fminf(v, __shfl_xor(v, m, 64));
    const int w = threadIdx.x >> 6;
    if ((threadIdx.x & 63) == 0) red[w] = v;
    __syncthreads();
    v = fminf(fminf(red[0], red[1]), fminf(red[2], red[3]));
    __syncthreads();
    return v;
}
__device__ __forceinline__ float blk_max(float v, float* red) {
#pragma unroll
    for (int m = 32; m; m >>= 1) v = fmaxf(v, __shfl_xor(v, m, 64));
    const int w = threadIdx.x >> 6;
    if ((threadIdx.x & 63) == 0) red[w] = v;
    __syncthreads();
    v = fmaxf(fmaxf(red[0], red[1]), fmaxf(red[2], red[3]));
    __syncthreads();
    return v;
}

// ---------- K1: normalize rows -> bf16, one-hot -> index, zero out ----------
__global__ __launch_bounds__(256) void prep_kernel(
    const float* __restrict__ feats, const float* __restrict__ labels,
    ushort_t* __restrict__ fn, int* __restrict__ lab, float* __restrict__ out)
{
    __shared__ float red[4];
    const int r = blockIdx.x, t = threadIdx.x;
    const float v0 = feats[(size_t)r * DIM + t];
    const float v1 = feats[(size_t)r * DIM + t + 256];
    const float ss = blk_sum(v0 * v0 + v1 * v1, red);
    const float sc = rsqrtf(ss);
    __hip_bfloat16 b0 = __float2bfloat16(v0 * sc);
    __hip_bfloat16 b1 = __float2bfloat16(v1 * sc);
    fn[(size_t)r * DIM + t]       = *(ushort_t*)&b0;
    fn[(size_t)r * DIM + t + 256] = *(ushort_t*)&b1;
    if (t < NCLS && labels[(size_t)r * NCLS + t] > 0.5f) lab[r] = t;
    if (r == 0 && t == 0) out[0] = 0.0f;
}

// ---------- K2: sim = F * F^T, bf16 MFMA, 128x128 tile, m97 structure ----------
#define BM 128
#define BK 32
#define NKSTEP (DIM / BK)   // 16

__global__ __launch_bounds__(256) void gemm_sim(
    const ushort_t* __restrict__ F, float* __restrict__ C)
{
    __shared__ __align__(16) ushort_t sA[2][BM * BK];
    __shared__ __align__(16) ushort_t sB[2][BM * BK];
    const int t = threadIdx.x;
    const int w = t >> 6, l = t & 63;
    const int brow = blockIdx.y * BM, bcol = blockIdx.x * BM;
    const int wr = w >> 1, wc = w & 1;          // 2x2 waves -> 64x64 each

    const int lr    = l >> 2;                   // row within 16-row staging chunk
    const int lslot = l & 3;                    // 16B slot within 64B row

    f32x4 acc[4][4];
    const f32x4 fz = {0.f, 0.f, 0.f, 0.f};
#pragma unroll
    for (int m = 0; m < 4; ++m)
#pragma unroll
        for (int n = 0; n < 4; ++n) acc[m][n] = fz;

    // stage one 128x32 bf16 tile for A and B; LDS linear [row][32],
    // global source pre-swizzled so reads use slot ^ ((row>>1)&3)
    auto stage = [&](int buf, int kb) {
#pragma unroll
        for (int i = 0; i < 2; ++i) {
            const int c   = w * 2 + i;          // chunk 0..7 (16 rows each)
            const int row = c * 16 + lr;        // tile-relative row
            const int kc  = lslot ^ ((row >> 1) & 3);
            async_load16(F + (size_t)(brow + row) * DIM + kb + kc * 8, &sA[buf][c * 512]);
            async_load16(F + (size_t)(bcol + row) * DIM + kb + kc * 8, &sB[buf][c * 512]);
        }
    };

    stage(0, 0);
    __syncthreads();                            // vmcnt(0) drained by compiler
    int cur = 0;
    for (int ks = 0; ks < NKSTEP; ++ks) {
        if (ks + 1 < NKSTEP) stage(cur ^ 1, (ks + 1) * BK);   // overlap with compute
        short8 av[4], bv[4];
#pragma unroll
        for (int m = 0; m < 4; ++m) {
            const int r    = wr * 64 + m * 16 + (l & 15);
            const int slot = (l >> 4) ^ ((r >> 1) & 3);
            av[m] = *(const short8*)&sA[cur][r * BK + slot * 8];
        }
#pragma unroll
        for (int n = 0; n < 4; ++n) {
            const int r    = wc * 64 + n * 16 + (l & 15);
            const int slot = (l >> 4) ^ ((r >> 1) & 3);
            bv[n] = *(const short8*)&sB[cur][r * BK + slot * 8];
        }
#pragma unroll
        for (int m = 0; m < 4; ++m)
#pragma unroll
            for (int n = 0; n < 4; ++n)
                acc[m][n] = __builtin_amdgcn_mfma_f32_16x16x32_bf16(av[m], bv[n], acc[m][n], 0, 0, 0);
        __syncthreads();                        // reads done + next stage drained
        cur ^= 1;
    }

    // epilogue: C/D layout col = l&15, row = (l>>4)*4 + r
#pragma unroll
    for (int m = 0; m < 4; ++m) {
        const int row0 = brow + wr * 64 + m * 16 + ((l >> 4) << 2);
#pragma unroll
        for (int n = 0; n < 4; ++n) {
            const int col = bcol + wc * 64 + n * 16 + (l & 15);
            float* cp = C + (size_t)row0 * B_N + col;
#pragma unroll
            for (int r = 0; r < 4; ++r) cp[(size_t)r * B_N] = acc[m][n][r];
        }
    }
}

// ---------- K3: per-row mining + loss, one block per row ----------
__global__ __launch_bounds__(256) void row_loss_kernel(
    const float* __restrict__ C, const int* __restrict__ lab, float* __restrict__ out)
{
    __shared__ float red[4];
    const int i = blockIdx.x, t = threadIdx.x;
    const int li = lab[i];
    const float4* cp = (const float4*)(C + (size_t)i * B_N);
    const int4*   lp = (const int4*)lab;

    float sv[16];
    int   lv[16];
#pragma unroll
    for (int q = 0; q < 4; ++q) {
        const int idx = t + 256 * q;
        const float4 a = cp[idx];
        const int4   b = lp[idx];
        sv[q * 4 + 0] = a.x; sv[q * 4 + 1] = a.y; sv[q * 4 + 2] = a.z; sv[q * 4 + 3] = a.w;
        lv[q * 4 + 0] = b.x; lv[q * 4 + 1] = b.y; lv[q * 4 + 2] = b.z; lv[q * 4 + 3] = b.w;
    }

    // pass 1: pos_min over same-label pairs (excl. self / sim>=1-eps)
    float pmin = 3.0e38f;
#pragma unroll
    for (int k = 0; k < 16; ++k) {
        const int j = 4 * t + 1024 * (k >> 2) + (k & 3);
        if (lv[k] == li && j != i && sv[k] < ONE_EPS) pmin = fminf(pmin, sv[k]);
    }
    pmin = blk_min(pmin, red);

    // pass 2: neg_max over kept negatives
    float nmax = -3.0e38f;
#pragma unroll
    for (int k = 0; k < 16; ++k) {
        if (lv[k] != li && sv[k] + MARGIN > pmin) nmax = fmaxf(nmax, sv[k]);
    }
    nmax = blk_max(nmax, red);

    // pass 3: masked exp sums + keep counts
    float ps = 0.f, ns = 0.f, pc = 0.f, nc = 0.f;
#pragma unroll
    for (int k = 0; k < 16; ++k) {
        const int j = 4 * t + 1024 * (k >> 2) + (k & 3);
        const float x = sv[k];
        if (lv[k] == li) {
            if (j != i && x < ONE_EPS && x - MARGIN < nmax) { ps += expf(-2.0f * (x - 0.5f)); pc += 1.f; }
        } else {
            if (x + MARGIN > pmin) { ns += expf(40.0f * (x - 0.5f)); nc += 1.f; }
        }
    }
    ps = blk_sum(ps, red);
    ns = blk_sum(ns, red);
    pc = blk_sum(pc, red);
    nc = blk_sum(nc, red);

    if (t == 0 && pc > 0.5f && nc > 0.5f) {
        const float loss = log1pf(ps) * 0.5f + log1pf(ns) * 0.025f;
        atomicAdd(out, loss * (1.0f / (float)B_N));
    }
}

extern "C" void kernel_launch(void* const* d_in, const int* in_sizes, int n_in,
                              void* d_out, int out_size, void* d_ws, size_t ws_size,
                              hipStream_t stream) {
    const float* feats  = (const float*)d_in[0];
    const float* labels = (const float*)d_in[1];
    float* out = (float*)d_out;

    // ws layout: fnorm bf16 [4096*512] = 4 MB | lab int[4096] = 16 KB | sim f32 [4096*4096] = 64 MB
    char* ws = (char*)d_ws;
    ushort_t* fn  = (ushort_t*)ws;
    int*      lab = (int*)(ws + (size_t)B_N * DIM * 2);
    float*    C   = (float*)(ws + (size_t)B_N * DIM * 2 + (size_t)B_N * 4);

    prep_kernel<<<B_N, 256, 0, stream>>>(feats, labels, fn, lab, out);
    dim3 g2(B_N / BM, B_N / BM);
    gemm_sim<<<g2, 256, 0, stream>>>(fn, C);
    row_loss_kernel<<<B_N, 256, 0, stream>>>(C, lab, out);
}